// Round 16
// baseline (26269.937 us; speedup 1.0000x reference)
//
#include <hip/hip_runtime.h>
#include <math.h>

#define HB 262144            // 512*512 shorts
#define LOG2PI 1.8378770664093453f

typedef __attribute__((ext_vector_type(8))) short bfrag;   // 8 bf16
typedef __attribute__((ext_vector_type(4))) float f32x4;
typedef __attribute__((ext_vector_type(4))) unsigned int u32x4;

#define MFMA(a,b,c) __builtin_amdgcn_mfma_f32_16x16x32_bf16(a,b,c,0,0,0)
#define ASTORE(p,v) __hip_atomic_store((p),(v),__ATOMIC_RELAXED,__HIP_MEMORY_SCOPE_AGENT)
#define ALOAD(p)    __hip_atomic_load((p),__ATOMIC_RELAXED,__HIP_MEMORY_SCOPE_AGENT)

// sc1 16B store: lands at L3, visible cross-XCD after vmcnt drain (r6-15 proven)
__device__ __forceinline__ void st16_sc1(void* p, u32x4 v){
  asm volatile("global_store_dwordx4 %0, %1, off sc1" :: "v"(p), "v"(v) : "memory");
}
// volatile 16B load: reads L3 coherence point, no fence needed (r9/r15 proven)
__device__ __forceinline__ u32x4 vld16u(const unsigned short* p){
  return *(const volatile u32x4*)p;
}
__device__ __forceinline__ void waitflag(unsigned* f, unsigned tgt){
  unsigned spin = 0;
  while (ALOAD(f) < tgt) {
    if (++spin > (1u<<16)) break;       // ~30ms cap: never hang harness
    __builtin_amdgcn_s_sleep(8);
  }
}

__device__ __forceinline__ float sigm(float x){ return 1.0f/(1.0f+__expf(-x)); }
__device__ __forceinline__ unsigned short f2bf(float f){
  unsigned int u = __builtin_bit_cast(unsigned int, f);
  u += 0x7FFFu + ((u>>16)&1u);          // RNE
  return (unsigned short)(u>>16);
}

struct Params {
  const float *states, *zin;
  const float *Wih0, *Whh0, *bih0, *bhh0;
  const float *Wih1, *Whh1, *bih1, *bhh1;
  const float *Wfc1, *bfc1, *Wfc2, *bfc2;
  const float *Wmean, *bmean, *Wlv, *blv;
  unsigned short *ws;
  float *out;
};

// ws layout (shorts):
//  wih0 @0 (98304) | whh0 @98304 (786432) | wih1 @884736 | whh1 @1671168
//  wfc1 @2457600 (311296) | wfc2 @2768896 (262144) | whead @3031040 (32768)
//  zbf @3063808 (32768) | h0G @3096576 (4*HB) | h1G @+4HB | d1G @+8HB
//  gmaster f32 @ short 6242304 (32 blocks x 16384 f32 = 2MB) | flags after
#define WIH0 0
#define WHH0 98304
#define WIH1 884736
#define WHH1 1671168
#define WFC1 2457600
#define WFC2 2768896
#define WHEAD 3031040
#define ZBF  3063808
#define GOFF 3096576

__global__ __launch_bounds__(256) void convertK(Params P){
  const float* src = nullptr; size_t dst = 0; int n = 0;
  switch (blockIdx.y) {
    case 0: src=P.Wih0;  dst=WIH0;        n=98304;  break;
    case 1: src=P.Whh0;  dst=WHH0;        n=786432; break;
    case 2: src=P.Wih1;  dst=WIH1;        n=786432; break;
    case 3: src=P.Whh1;  dst=WHH1;        n=786432; break;
    case 4: src=P.Wfc1;  dst=WFC1;        n=311296; break;
    case 5: src=P.Wfc2;  dst=WFC2;        n=262144; break;
    case 6: src=P.Wmean; dst=WHEAD;       n=16384;  break;
    case 7: src=P.Wlv;   dst=WHEAD+16384; n=16384;  break;
    case 8: src=P.zin;   dst=ZBF;         n=32768;  break;
  }
  unsigned short* d = P.ws + dst;
  for (int i = blockIdx.x*256 + threadIdx.x; i < n; i += gridDim.x*256)
    d[i] = f2bf(src[i]);
}

// Roles (xg=blk&7, k=blk>>3), M=32 batch rows per block, rows = g*32:
//  gru1: xg<4, k<4,  g=k*4+xg   (16 blocks, XCDs 0-3)
//  gru0: xg in {4,5}, k<8, g=(xg-4)*8+k (16 blocks, XCDs 4-5)
//  fc1:  xg==6, g=k            (16 blocks, XCD 6)
//  fc2+head: xg==7, g=k        (16 blocks, XCD 7)
// Recurrence is INTRA-BLOCK (LDS bf16 dbuf + block-private f32 master).
// Cross-role edges: sc1 publish + volatile copy-in, 1:1 single-flag waits.
__global__ __launch_bounds__(256, 1) void fused(Params P, unsigned* flags){
  __shared__ unsigned short sm[49920];   // 99840 B
  const int tid  = threadIdx.x;
  const int lane = tid & 63;
  const int wv   = tid >> 6;
  const int r16  = lane & 15, kg = lane >> 4;
  const int blk  = blockIdx.x;
  const int xg   = blk & 7, k = blk >> 3;

  unsigned short* h0G = P.ws + GOFF;
  unsigned short* h1G = P.ws + GOFF + 4*(size_t)HB;
  unsigned short* d1G = P.ws + GOFF + 8*(size_t)HB;
  float* gmall = (float*)(P.ws + GOFF + 12*(size_t)HB);

  if (xg < 4) {
    // ============================ gru1 ============================
    if (k >= 4) return;
    const int g = k*4 + xg;
    const int R = g*32;
    unsigned* fOwn  = &flags[blk*16];
    unsigned* fGru0 = &flags[(4 + (g>>3) + 8*(g&7))*16];
    unsigned* fFc1  = &flags[(6 + 8*g)*16];
    float* gm = gmall + (size_t)(16 + g)*16384;     // [32][512] f32 master
    // LDS: hb[2][32][520] @0 ; h0in[32][520] @33280
    for (int c = tid; c < 16640; c += 256) sm[c] = 0;   // hb[0] = h1(-1) = 0
    int cur = 0;
    for (int s = 0; s < 254; ++s) {
      if (tid == 0) {
        waitflag(fGru0, (unsigned)(s+1));             // h0(s) ready
        if (s >= 3) waitflag(fFc1, (unsigned)(s-2));  // WAR h1G slot
      }
      __syncthreads();
      { // copy h0(s) rows R..R+32 -> h0in (volatile from L3)
        const unsigned short* src = h0G + (size_t)(s&3)*HB + (size_t)R*512;
        int r = tid>>3, c0 = (tid&7)*64;
        #pragma unroll
        for (int q = 0; q < 8; ++q)
          *(u32x4*)&sm[33280 + r*520 + c0 + q*8] = vld16u(src + (size_t)r*512 + c0 + q*8);
      }
      __syncthreads();
      unsigned short* hbC = sm + cur*16640;
      unsigned short* hbN = sm + (cur^1)*16640;
      for (int jl = 0; jl < 8; ++jl) {
        const int n = (wv*8 + jl)*16 + r16;
        f32x4 Ra[2]={}, Za[2]={}, NIa[2]={}, NHa[2]={};
        const unsigned short* ir = P.ws + WIH1 + (size_t)(      n)*512;
        const unsigned short* iz = P.ws + WIH1 + (size_t)( 512 + n)*512;
        const unsigned short* in_= P.ws + WIH1 + (size_t)(1024 + n)*512;
        #pragma unroll 4
        for (int kt = 0; kt < 16; ++kt) {             // gi half: A = h0(s)
          const int kk = kt*32 + kg*8;
          bfrag a0 = *(const bfrag*)&sm[33280 + r16*520 + kk];
          bfrag a1 = *(const bfrag*)&sm[33280 + (r16+16)*520 + kk];
          bfrag bR = *(const bfrag*)&ir[kk];
          bfrag bZ = *(const bfrag*)&iz[kk];
          bfrag bN = *(const bfrag*)&in_[kk];
          Ra[0]=MFMA(a0,bR,Ra[0]); Ra[1]=MFMA(a1,bR,Ra[1]);
          Za[0]=MFMA(a0,bZ,Za[0]); Za[1]=MFMA(a1,bZ,Za[1]);
          NIa[0]=MFMA(a0,bN,NIa[0]); NIa[1]=MFMA(a1,bN,NIa[1]);
        }
        const unsigned short* hr = P.ws + WHH1 + (size_t)(      n)*512;
        const unsigned short* hz = P.ws + WHH1 + (size_t)( 512 + n)*512;
        const unsigned short* hn_= P.ws + WHH1 + (size_t)(1024 + n)*512;
        #pragma unroll 4
        for (int kt = 0; kt < 16; ++kt) {             // gh half: A = h1(s-1)
          const int kk = kt*32 + kg*8;
          bfrag a0 = *(const bfrag*)&hbC[r16*520 + kk];
          bfrag a1 = *(const bfrag*)&hbC[(r16+16)*520 + kk];
          bfrag bR = *(const bfrag*)&hr[kk];
          bfrag bZ = *(const bfrag*)&hz[kk];
          bfrag bN = *(const bfrag*)&hn_[kk];
          Ra[0]=MFMA(a0,bR,Ra[0]); Ra[1]=MFMA(a1,bR,Ra[1]);
          Za[0]=MFMA(a0,bZ,Za[0]); Za[1]=MFMA(a1,bZ,Za[1]);
          NHa[0]=MFMA(a0,bN,NHa[0]); NHa[1]=MFMA(a1,bN,NHa[1]);
        }
        const float b0 = P.bih1[n] + P.bhh1[n];
        const float b1 = P.bih1[n+512] + P.bhh1[n+512];
        const float b2 = P.bih1[n+1024], b3 = P.bhh1[n+1024];
        #pragma unroll
        for (int fm = 0; fm < 2; ++fm)
          #pragma unroll
          for (int e = 0; e < 4; ++e) {
            int row = fm*16 + kg*4 + e;
            float r_ = sigm(Ra[fm][e] + b0);
            float z_ = sigm(Za[fm][e] + b1);
            float nn = tanhf(NIa[fm][e] + b2 + r_*(NHa[fm][e] + b3));
            float hold = gm[row*512 + n];
            float hnv = (1.f - z_)*nn + z_*hold;
            gm[row*512 + n] = hnv;
            hbN[row*520 + n] = f2bf(hnv);
          }
      }
      __syncthreads();
      { // publish h1(s) -> h1G[s&3]
        unsigned short* dst = h1G + (size_t)(s&3)*HB + (size_t)R*512;
        int r = tid>>3, c0 = (tid&7)*64;
        #pragma unroll
        for (int q = 0; q < 8; ++q) {
          u32x4 v = *(const u32x4*)&sm[(cur^1)*16640 + r*520 + c0 + q*8];
          st16_sc1(dst + (size_t)r*512 + c0 + q*8, v);
        }
      }
      __syncthreads();
      if (tid == 0) ASTORE(fOwn, (unsigned)(s+1));
      cur ^= 1;
    }
  } else if (xg < 6) {
    // ============================ gru0 ============================
    if (k >= 8) return;
    const int g = (xg-4)*8 + k;
    const int R = g*32;
    unsigned* fOwn  = &flags[blk*16];
    unsigned* fGru1 = &flags[((g&3) + 8*(g>>2))*16];
    float* gm = gmall + (size_t)g*16384;
    // LDS: hb[2][32][520] @0 ; sA[32][72] @33280
    for (int c = tid; c < 16640; c += 256) sm[c] = 0;   // hb[0] = h0(-1) = 0
    int cur = 0;
    for (int s = 0; s < 254; ++s) {
      if (tid == 0 && s >= 4) waitflag(fGru1, (unsigned)(s-3));  // WAR h0G slot
      __syncthreads();
      { // stage x = [s(s), a(s)] bf16 -> sA
        const float* s0 = P.states + (size_t)s*512*32;
        int i0 = tid*8;
        #pragma unroll
        for (int q = 0; q < 8; ++q) {
          int idx = i0 + q, r = idx>>6, c = idx&63;
          float v = (c < 32) ? s0[(size_t)(R+r)*32 + c]
                             : (s0[(size_t)(512 + R + r)*32 + (c-32)] - s0[(size_t)(R+r)*32 + (c-32)]);
          sm[33280 + r*72 + c] = f2bf(v);
        }
      }
      __syncthreads();
      unsigned short* hbC = sm + cur*16640;
      unsigned short* hbN = sm + (cur^1)*16640;
      for (int jl = 0; jl < 8; ++jl) {
        const int n = (wv*8 + jl)*16 + r16;
        f32x4 Ra[2]={}, Za[2]={}, NIa[2]={}, NHa[2]={};
        const unsigned short* ir = P.ws + WIH0 + (size_t)(      n)*64;
        const unsigned short* iz = P.ws + WIH0 + (size_t)( 512 + n)*64;
        const unsigned short* in_= P.ws + WIH0 + (size_t)(1024 + n)*64;
        #pragma unroll
        for (int kt = 0; kt < 2; ++kt) {              // x part K=64
          const int kk = kt*32 + kg*8;
          bfrag a0 = *(const bfrag*)&sm[33280 + r16*72 + kk];
          bfrag a1 = *(const bfrag*)&sm[33280 + (r16+16)*72 + kk];
          bfrag bR = *(const bfrag*)&ir[kk];
          bfrag bZ = *(const bfrag*)&iz[kk];
          bfrag bN = *(const bfrag*)&in_[kk];
          Ra[0]=MFMA(a0,bR,Ra[0]); Ra[1]=MFMA(a1,bR,Ra[1]);
          Za[0]=MFMA(a0,bZ,Za[0]); Za[1]=MFMA(a1,bZ,Za[1]);
          NIa[0]=MFMA(a0,bN,NIa[0]); NIa[1]=MFMA(a1,bN,NIa[1]);
        }
        const unsigned short* hr = P.ws + WHH0 + (size_t)(      n)*512;
        const unsigned short* hz = P.ws + WHH0 + (size_t)( 512 + n)*512;
        const unsigned short* hn_= P.ws + WHH0 + (size_t)(1024 + n)*512;
        #pragma unroll 4
        for (int kt = 0; kt < 16; ++kt) {             // h part K=512
          const int kk = kt*32 + kg*8;
          bfrag a0 = *(const bfrag*)&hbC[r16*520 + kk];
          bfrag a1 = *(const bfrag*)&hbC[(r16+16)*520 + kk];
          bfrag bR = *(const bfrag*)&hr[kk];
          bfrag bZ = *(const bfrag*)&hz[kk];
          bfrag bN = *(const bfrag*)&hn_[kk];
          Ra[0]=MFMA(a0,bR,Ra[0]); Ra[1]=MFMA(a1,bR,Ra[1]);
          Za[0]=MFMA(a0,bZ,Za[0]); Za[1]=MFMA(a1,bZ,Za[1]);
          NHa[0]=MFMA(a0,bN,NHa[0]); NHa[1]=MFMA(a1,bN,NHa[1]);
        }
        const float b0 = P.bih0[n] + P.bhh0[n];
        const float b1 = P.bih0[n+512] + P.bhh0[n+512];
        const float b2 = P.bih0[n+1024], b3 = P.bhh0[n+1024];
        #pragma unroll
        for (int fm = 0; fm < 2; ++fm)
          #pragma unroll
          for (int e = 0; e < 4; ++e) {
            int row = fm*16 + kg*4 + e;
            float r_ = sigm(Ra[fm][e] + b0);
            float z_ = sigm(Za[fm][e] + b1);
            float nn = tanhf(NIa[fm][e] + b2 + r_*(NHa[fm][e] + b3));
            float hold = gm[row*512 + n];
            float hnv = (1.f - z_)*nn + z_*hold;
            gm[row*512 + n] = hnv;
            hbN[row*520 + n] = f2bf(hnv);
          }
      }
      __syncthreads();
      { // publish h0(s) -> h0G[s&3]
        unsigned short* dst = h0G + (size_t)(s&3)*HB + (size_t)R*512;
        int r = tid>>3, c0 = (tid&7)*64;
        #pragma unroll
        for (int q = 0; q < 8; ++q) {
          u32x4 v = *(const u32x4*)&sm[(cur^1)*16640 + r*520 + c0 + q*8];
          st16_sc1(dst + (size_t)r*512 + c0 + q*8, v);
        }
      }
      __syncthreads();
      if (tid == 0) ASTORE(fOwn, (unsigned)(s+1));
      cur ^= 1;
    }
  } else if (xg == 6) {
    // ============================ fc1 ============================
    const int g = k;
    const int R = g*32;
    unsigned* fOwn  = &flags[blk*16];
    unsigned* fGru1 = &flags[((g&3) + 8*(g>>2))*16];
    unsigned* fFc2  = &flags[(7 + 8*g)*16];
    // LDS: h1in[32][520]@0, zA[32][72]@16640, sS[32][40]@18944, exch[32][520]@20224
    for (int c = tid; c < 2048; c += 256) {
      int r = c>>6, cc = c&63;
      sm[16640 + r*72 + cc] = P.ws[ZBF + (size_t)(R+r)*64 + cc];
    }
    for (int s = 0; s < 254; ++s) {
      if (tid == 0) {
        if (s >= 1) waitflag(fGru1, (unsigned)s);       // h1(s-1) ready
        if (s >= 3) waitflag(fFc2, (unsigned)(s-2));    // WAR d1G slot
      }
      __syncthreads();
      if (s >= 1) { // copy h1(s-1) rows -> h1in
        const unsigned short* src = h1G + (size_t)((s-1)&3)*HB + (size_t)R*512;
        int r = tid>>3, c0 = (tid&7)*64;
        #pragma unroll
        for (int q = 0; q < 8; ++q)
          *(u32x4*)&sm[r*520 + c0 + q*8] = vld16u(src + (size_t)r*512 + c0 + q*8);
      } else {
        for (int c = tid; c < 16640; c += 256) sm[c] = 0;
      }
      { // stage s(s) rows bf16 -> sS
        const float* s0 = P.states + (size_t)s*512*32;
        int i0 = tid*4;
        #pragma unroll
        for (int q = 0; q < 4; ++q) {
          int idx = i0 + q, r = idx>>5, c = idx&31;
          sm[18944 + r*40 + c] = f2bf(s0[(size_t)(R+r)*32 + c]);
        }
      }
      __syncthreads();
      for (int nl = 0; nl < 8; ++nl) {
        const int n = (wv*8 + nl)*16 + r16;
        f32x4 acc[2] = {};
        const unsigned short* wb = P.ws + WFC1 + (size_t)n*608;
        #pragma unroll
        for (int kt = 0; kt < 19; ++kt) {
          const int kk = kt*32 + kg*8;
          bfrag a0, a1;
          if (kt == 0) {
            a0 = *(const bfrag*)&sm[18944 + r16*40 + kg*8];
            a1 = *(const bfrag*)&sm[18944 + (r16+16)*40 + kg*8];
          } else if (kt <= 2) {
            a0 = *(const bfrag*)&sm[16640 + r16*72 + (kk-32)];
            a1 = *(const bfrag*)&sm[16640 + (r16+16)*72 + (kk-32)];
          } else {
            a0 = *(const bfrag*)&sm[r16*520 + (kk-96)];
            a1 = *(const bfrag*)&sm[(r16+16)*520 + (kk-96)];
          }
          bfrag b = *(const bfrag*)&wb[kk];
          acc[0] = MFMA(a0, b, acc[0]);
          acc[1] = MFMA(a1, b, acc[1]);
        }
        const float bias = P.bfc1[n];
        #pragma unroll
        for (int fm = 0; fm < 2; ++fm)
          #pragma unroll
          for (int e = 0; e < 4; ++e) {
            int row = fm*16 + kg*4 + e;
            sm[20224 + row*520 + n] = f2bf(fmaxf(acc[fm][e] + bias, 0.f));
          }
      }
      __syncthreads();
      { // publish dh1(s) -> d1G[s&3]
        unsigned short* dst = d1G + (size_t)(s&3)*HB + (size_t)R*512;
        int r = tid>>3, c0 = (tid&7)*64;
        #pragma unroll
        for (int q = 0; q < 8; ++q) {
          u32x4 v = *(const u32x4*)&sm[20224 + r*520 + c0 + q*8];
          st16_sc1(dst + (size_t)r*512 + c0 + q*8, v);
        }
      }
      __syncthreads();
      if (tid == 0) ASTORE(fOwn, (unsigned)(s+1));
    }
  } else {
    // ============================ fc2 + head ============================
    const int g = k;
    const int R = g*32;
    unsigned* fOwn = &flags[blk*16];
    unsigned* fFc1 = &flags[(6 + 8*g)*16];
    // LDS: d1in[32][520]@0, dh2[32][520]@16640
    const int fmH = wv & 1;
    const int iH  = (wv>>1)*16 + r16;       // 0..31
    const float bm = P.bmean[iH], bl = P.blv[iH];
    float nll[4] = {0.f, 0.f, 0.f, 0.f};
    for (int s = 0; s < 254; ++s) {
      if (tid == 0) waitflag(fFc1, (unsigned)(s+1));    // dh1(s) ready
      __syncthreads();
      { // copy dh1(s) rows -> d1in
        const unsigned short* src = d1G + (size_t)(s&3)*HB + (size_t)R*512;
        int r = tid>>3, c0 = (tid&7)*64;
        #pragma unroll
        for (int q = 0; q < 8; ++q)
          *(u32x4*)&sm[r*520 + c0 + q*8] = vld16u(src + (size_t)r*512 + c0 + q*8);
      }
      __syncthreads();
      for (int nl = 0; nl < 8; ++nl) {
        const int n = (wv*8 + nl)*16 + r16;
        f32x4 acc[2] = {};
        const unsigned short* wb = P.ws + WFC2 + (size_t)n*512;
        #pragma unroll 4
        for (int kt = 0; kt < 16; ++kt) {
          const int kk = kt*32 + kg*8;
          bfrag a0 = *(const bfrag*)&sm[r16*520 + kk];
          bfrag a1 = *(const bfrag*)&sm[(r16+16)*520 + kk];
          bfrag b = *(const bfrag*)&wb[kk];
          acc[0] = MFMA(a0, b, acc[0]);
          acc[1] = MFMA(a1, b, acc[1]);
        }
        const float bias = P.bfc2[n];
        #pragma unroll
        for (int fm = 0; fm < 2; ++fm)
          #pragma unroll
          for (int e = 0; e < 4; ++e) {
            int row = fm*16 + kg*4 + e;
            sm[16640 + row*520 + n] = f2bf(fmaxf(acc[fm][e] + bias, 0.f));
          }
      }
      __syncthreads();
      { // head: mean/lv for 16 rows x 16 i per wave
        f32x4 aM = {}, aL = {};
        const unsigned short* wm = P.ws + WHEAD + (size_t)iH*512;
        const unsigned short* wl = P.ws + WHEAD + (size_t)(32 + iH)*512;
        #pragma unroll 4
        for (int kt = 0; kt < 16; ++kt) {
          const int kk = kt*32 + kg*8;
          bfrag a = *(const bfrag*)&sm[16640 + (fmH*16 + r16)*520 + kk];
          aM = MFMA(a, *(const bfrag*)&wm[kk], aM);
          aL = MFMA(a, *(const bfrag*)&wl[kk], aL);
        }
        const float* s0 = P.states + (size_t)s*512*32;
        #pragma unroll
        for (int e = 0; e < 4; ++e) {
          int row = R + fmH*16 + kg*4 + e;
          float mean = aM[e] + bm, lv = aL[e] + bl;
          float av = s0[(size_t)(512 + row)*32 + iH] - s0[(size_t)row*32 + iH];
          float d = av - mean;
          nll[e] += 0.5f*(d*d*__expf(-lv) + lv + LOG2PI);
        }
      }
      __syncthreads();
      if (tid == 0) ASTORE(fOwn, (unsigned)(s+1));
    }
    #pragma unroll
    for (int e = 0; e < 4; ++e) {
      int row = R + fmH*16 + kg*4 + e;
      P.out[(size_t)row*32 + iH] = nll[e];
    }
  }
}

extern "C" void kernel_launch(void* const* d_in, const int* in_sizes, int n_in,
                              void* d_out, int out_size, void* d_ws, size_t ws_size,
                              hipStream_t stream) {
  Params P;
  P.states = (const float*)d_in[0];
  P.zin    = (const float*)d_in[1];
  P.Wih0   = (const float*)d_in[2];
  P.Whh0   = (const float*)d_in[3];
  P.bih0   = (const float*)d_in[4];
  P.bhh0   = (const float*)d_in[5];
  P.Wih1   = (const float*)d_in[6];
  P.Whh1   = (const float*)d_in[7];
  P.bih1   = (const float*)d_in[8];
  P.bhh1   = (const float*)d_in[9];
  P.Wfc1   = (const float*)d_in[10];
  P.bfc1   = (const float*)d_in[11];
  P.Wfc2   = (const float*)d_in[12];
  P.bfc2   = (const float*)d_in[13];
  P.Wmean  = (const float*)d_in[14];
  P.bmean  = (const float*)d_in[15];
  P.Wlv    = (const float*)d_in[16];
  P.blv    = (const float*)d_in[17];
  P.out = (float*)d_out;
  P.ws  = (unsigned short*)d_ws;

  float* gmaster  = (float*)(P.ws + GOFF + 12*(size_t)HB);
  unsigned* flags = (unsigned*)(gmaster + 32*(size_t)16384);

  hipMemsetAsync(gmaster, 0, 32*(size_t)16384*sizeof(float), stream);  // h(-1)=0
  hipMemsetAsync(flags, 0, 128*16*sizeof(unsigned), stream);
  hipMemsetAsync(d_out, 0, (size_t)out_size*sizeof(float), stream);

  convertK<<<dim3(96, 9), 256, 0, stream>>>(P);
  fused<<<dim3(128), 256, 0, stream>>>(P, flags);
}

// Round 17
// 4002.659 us; speedup vs baseline: 6.5631x; 6.5631x over previous
//
#include <hip/hip_runtime.h>
#include <math.h>

#define BATCH 512
#define LOG2PI 1.8378770664093453f
#define HB 262144   // 512*512 shorts

typedef __attribute__((ext_vector_type(8))) short bfrag;   // 8 bf16
typedef __attribute__((ext_vector_type(4))) float f32x4;
typedef __attribute__((ext_vector_type(4))) unsigned int u32x4;

#define MFMA(a,b,c) __builtin_amdgcn_mfma_f32_16x16x32_bf16(a,b,c,0,0,0)
#define ASTORE(p,v) __hip_atomic_store((p),(v),__ATOMIC_RELAXED,__HIP_MEMORY_SCOPE_AGENT)
#define ALOAD(p)    __hip_atomic_load((p),__ATOMIC_RELAXED,__HIP_MEMORY_SCOPE_AGENT)

// 16B device-coherent store (sc1): data lands at L3, visible cross-XCD after
// vmcnt drain (proven rounds 6-15).
__device__ __forceinline__ void st16_sc1(void* p, u32x4 v){
  asm volatile("global_store_dwordx4 %0, %1, off sc1" :: "v"(p), "v"(v) : "memory");
}

__device__ __forceinline__ float sigm(float x){ return 1.0f/(1.0f+__expf(-x)); }
__device__ __forceinline__ unsigned short f2bf(float f){
  unsigned int u = __builtin_bit_cast(unsigned int, f);
  u += 0x7FFFu + ((u>>16)&1u);          // RNE
  return (unsigned short)(u>>16);
}
__device__ __forceinline__ bfrag cvt8(const float* __restrict__ p){
  bfrag v;
  #pragma unroll
  for (int e=0;e<8;++e) v[e] = (short)f2bf(p[e]);
  return v;
}
__device__ __forceinline__ bfrag cvt8d(const float* __restrict__ p1, const float* __restrict__ p0){
  bfrag v;
  #pragma unroll
  for (int e=0;e<8;++e) v[e] = (short)f2bf(p1[e]-p0[e]);
  return v;
}

struct Params {
  const float *states, *zin;
  const float *Wih0, *Whh0, *bih0, *bhh0;
  const float *Wih1, *Whh1, *bih1, *bhh1;
  const float *Wfc1, *bfc1, *Wfc2, *bfc2;
  const float *Wmean, *bmean, *Wlv, *blv;
  unsigned short *act;   // h0[8*HB] | h1[8*HB] | d1[8*HB] | d2[8*HB]
  float *out;
};

// Roles (xg = blk&7, sub = blk>>3):
//   xg 0-3: gru1  rows xg*128, j-tile=sub.  LDS: W [3][16][1032], exch@49536
//   xg 4-5: gru0  rows (xg-4)*256, j-tile=sub. LDS: W [3][16][584], exch@28032
//   xg 6:   fc1   bm=sub>>3, bn=sub&7. LDS: W [64][616], exch@39424, z@47616
//   xg 7:   fc2+head. LDS: W x2 @0/33280, exch@66560
// Sync: LEADER (sub==0) per xg does the union producer wait + full agent
// acquire fence (L1+L2 inv) ONCE per XCD per phase, publishes xcdf[xg].
// Followers poll xcdf then do an L1-only `buffer_inv` — L2 stays warm and
// shared across the XCD's 32 blocks.
__global__ __launch_bounds__(256, 1) void fused(Params P, unsigned* flags, unsigned* xcdf) {
  __shared__ unsigned short sm[74752];   // 149504 B static LDS
  const int tid  = threadIdx.x;
  const int lane = tid & 63;
  const int wv   = tid >> 6;
  const int r16  = lane & 15, kg = lane >> 4;
  const int blk  = blockIdx.x;
  const int xg   = blk & 7, sub = blk >> 3;

  unsigned short* h0 = P.act;
  unsigned short* h1 = P.act +  8*(size_t)HB;
  unsigned short* d1 = P.act + 16*(size_t)HB;
  unsigned short* d2 = P.act + 24*(size_t)HB;

  // ---------------- startup: stage weights (+z) into LDS (bf16) -----------
  if (xg < 4) {
    const int jt = sub;
    const float* Wsrc[2] = {P.Wih1, P.Whh1};
    #pragma unroll
    for (int m = 0; m < 2; ++m) {
      const float* W = Wsrc[m];
      for (int c = tid; c < 3072; c += 256) {
        int g = c >> 10, rem = c & 1023;
        int r = rem >> 6, k = (rem & 63) << 3;
        *(bfrag*)&sm[(g*16+r)*1032 + m*512 + k] =
          cvt8(&W[((size_t)(g*512 + jt*16 + r))*512 + k]);
      }
    }
  } else if (xg < 6) {
    const int jt = sub;
    for (int c = tid; c < 384; c += 256) {
      int g = c >> 7, rem = c & 127;
      int r = rem >> 3, k = (rem & 7) << 3;
      *(bfrag*)&sm[(g*16+r)*584 + k] =
        cvt8(&P.Wih0[((size_t)(g*512 + jt*16 + r))*64 + k]);
    }
    for (int c = tid; c < 3072; c += 256) {
      int g = c >> 10, rem = c & 1023;
      int r = rem >> 6, k = (rem & 63) << 3;
      *(bfrag*)&sm[(g*16+r)*584 + 64 + k] =
        cvt8(&P.Whh0[((size_t)(g*512 + jt*16 + r))*512 + k]);
    }
  } else if (xg == 6) {
    const int bn = (sub & 7) * 64;
    const int bmB = (sub >> 3) * 128;
    for (int c = tid; c < 4864; c += 256) {
      int n = c / 76, k = (c % 76) << 3;
      *(bfrag*)&sm[n*616 + k] = cvt8(&P.Wfc1[(size_t)(bn + n)*608 + k]);
    }
    for (int c = tid; c < 1024; c += 256) {      // z slice rows bmB..bmB+127
      int r = c >> 3, k = (c & 7) << 3;
      *(bfrag*)&sm[47616 + r*64 + k] = cvt8(&P.zin[(size_t)(bmB + r)*64 + k]);
    }
  } else {
    const int bn = (sub & 7) * 64;
    for (int c = tid; c < 4096; c += 256) {
      int n = c >> 6, k = (c & 63) << 3;
      *(bfrag*)&sm[n*520 + k] = cvt8(&P.Wfc2[(size_t)(bn + n)*512 + k]);
    }
    for (int c = tid; c < 4096; c += 256) {
      int m = c >> 6, k = (c & 63) << 3;
      const float* src = (m < 32) ? &P.Wmean[(size_t)m*512 + k]
                                  : &P.Wlv[(size_t)(m-32)*512 + k];
      *(bfrag*)&sm[33280 + m*520 + k] = cvt8(src);
    }
  }

  // ---------------- hoisted per-thread biases ----------------
  float b0 = 0.f, b1 = 0.f, b2 = 0.f, b3 = 0.f;
  if (xg < 4) {
    int j = sub*16 + r16;
    b0 = P.bih1[j] + P.bhh1[j];
    b1 = P.bih1[j+512] + P.bhh1[j+512];
    b2 = P.bih1[j+1024]; b3 = P.bhh1[j+1024];
  } else if (xg < 6) {
    int j = sub*16 + r16;
    b0 = P.bih0[j] + P.bhh0[j];
    b1 = P.bih0[j+512] + P.bhh0[j+512];
    b2 = P.bih0[j+1024]; b3 = P.bhh0[j+1024];
  } else if (xg == 6) {
    int nn0 = (sub & 7)*64 + (wv&1)*32 + r16;
    b0 = P.bfc1[nn0]; b1 = P.bfc1[nn0+16];
  } else {
    int nn0 = (sub & 7)*64 + (wv&1)*32 + r16;
    b0 = P.bfc2[nn0]; b1 = P.bfc2[nn0+16];
    int c = wv*16 + r16;
    b2 = (c < 32) ? P.bmean[c] : P.blv[c-32];
  }
  float hs[4][4] = {};                  // gru f32 master state (regs)
  float nacc0 = 0.f, nacc1 = 0.f;

  for (int u = 0; u <= 256; ++u) {
    // ---------- sync: leader union-wait + L2 inv; followers L1-only ----------
    if (sub == 0) {
      if (wv == 0) {
        int pb1 = -1, pb2 = -1, pb3 = -1;
        const unsigned t1 = (unsigned)u, t2 = (unsigned)(u - 6);
        if (xg >= 4 && xg < 6) {          // gru0: own>=u ; gru1 consumers >=u-6
          if (u >= 1 && lane < 32) pb1 = lane*8 + xg;
          if (u >= 7)              pb2 = (lane>>1)*8 + 2*(xg-4) + (lane&1);
        } else if (xg < 4) {              // gru1: own+gru0 >=u ; fc1 >=u-6
          if (u >= 1) pb1 = (lane < 32) ? lane*8 + xg : (lane-32)*8 + 4 + (xg>>1);
          if (u >= 7 && lane < 8) pb2 = (xg*8 + lane)*8 + 6;
        } else if (xg == 6) {             // fc1: ALL gru1 >=u ; ALL fc2 >=u-6
          if (u >= 1) { pb1 = (lane>>2)*8 + (lane&3); pb3 = pb1 + 128; }
          if (u >= 7 && lane < 32) pb2 = lane*8 + 7;
        } else {                          // fc2/head: ALL fc1 + ALL fc2 >=u
          if (u >= 1) pb1 = (lane < 32) ? lane*8 + 6 : (lane-32)*8 + 7;
        }
        unsigned spin = 0;
        while (true) {
          bool ok = true;
          if (pb1 >= 0) ok &= (ALOAD(&flags[pb1*16]) >= t1);
          if (pb3 >= 0) ok &= (ALOAD(&flags[pb3*16]) >= t1);
          if (pb2 >= 0) ok &= (ALOAD(&flags[pb2*16]) >= t2);
          if (__all(ok)) break;
          if (++spin > (1u<<26)) break;   // safety: never hang the harness
          __builtin_amdgcn_s_sleep(1);
        }
      }
      __syncthreads();
      if (tid < 64) __builtin_amdgcn_fence(__ATOMIC_ACQUIRE, "agent"); // L1+L2 inv
      __syncthreads();
      if (tid == 0) ASTORE(&xcdf[xg*16], (unsigned)(u+1));
    } else {
      if (wv == 0 && lane == 0) {
        unsigned spin = 0;
        while (ALOAD(&xcdf[xg*16]) < (unsigned)(u+1)) {
          if (++spin > (1u<<26)) break;   // safety
          __builtin_amdgcn_s_sleep(1);
        }
      }
      __syncthreads();
      if (tid < 64)
        asm volatile("buffer_inv\n\ts_waitcnt vmcnt(0)" ::: "memory"); // L1-only
      __syncthreads();
    }

    const int ju  = u & 7;              // slot of step u
    const int jm1 = (u+7) & 7;          // step u-1
    const int jm2 = (u+6) & 7;          // step u-2
    const int jm3 = (u+5) & 7;          // step u-3

    if (xg < 4) {
      // ---------------- gru1, step t = u-1 ----------------
      if (u >= 1 && u <= 254) {
        const int jt = sub, bmB = xg * 128;
        const unsigned short* h0r = h0 + (size_t)jm1*HB;   // h0(t)
        const unsigned short* h1r = h1 + (size_t)jm2*HB;   // h1(t-1)
        f32x4 R[2]={}, Z[2]={}, NI[2]={}, NH[2]={};
        const int row0 = bmB + wv*32 + r16;
        #pragma unroll
        for (int half = 0; half < 2; ++half) {
          const unsigned short* asrc = half ? h1r : h0r;
          #pragma unroll 4
          for (int kt = 0; kt < 16; ++kt) {
            const int kk = kt*32 + kg*8;
            const int kl = half*512 + kk;
            bfrag a0 = *(const bfrag*)&asrc[(size_t)row0*512 + kk];
            bfrag a1 = *(const bfrag*)&asrc[(size_t)(row0+16)*512 + kk];
            bfrag bR = *(const bfrag*)&sm[(0*16+r16)*1032 + kl];
            bfrag bZ = *(const bfrag*)&sm[(1*16+r16)*1032 + kl];
            bfrag bN = *(const bfrag*)&sm[(2*16+r16)*1032 + kl];
            R[0]=MFMA(a0,bR,R[0]); R[1]=MFMA(a1,bR,R[1]);
            Z[0]=MFMA(a0,bZ,Z[0]); Z[1]=MFMA(a1,bZ,Z[1]);
            if (!half) { NI[0]=MFMA(a0,bN,NI[0]); NI[1]=MFMA(a1,bN,NI[1]); }
            else       { NH[0]=MFMA(a0,bN,NH[0]); NH[1]=MFMA(a1,bN,NH[1]); }
          }
        }
        unsigned short* exch = sm + 49536;          // [128][16]
        #pragma unroll
        for (int fm = 0; fm < 2; ++fm)
          #pragma unroll
          for (int e = 0; e < 4; ++e) {
            int rl = wv*32 + fm*16 + kg*4 + e;
            float r  = sigm(R[fm][e] + b0);
            float zg = sigm(Z[fm][e] + b1);
            float nn = tanhf(NI[fm][e] + b2 + r*(NH[fm][e] + b3));
            float hn = (1.f - zg)*nn + zg*hs[fm][e];
            hs[fm][e] = hn;
            exch[rl*16 + r16] = f2bf(hn);
          }
        __syncthreads();
        {
          unsigned short* dst = h1 + (size_t)jm1*HB;       // h1(t) = step u-1
          int r = tid >> 1, hc = tid & 1;
          u32x4 v = *(const u32x4*)&exch[r*16 + hc*8];
          st16_sc1(dst + ((size_t)(bmB + r))*512 + jt*16 + hc*8, v);
        }
      }
    } else if (xg < 6) {
      // ---------------- gru0, step t = u ----------------
      if (u <= 253) {
        const int jt = sub, bmB = (xg - 4) * 256;
        const unsigned short* h0r = h0 + (size_t)jm1*HB;   // h0(t-1)
        const float* s0p = P.states + (size_t)u*BATCH*32;
        f32x4 R[4]={}, Z[4]={}, NI[4]={}, NH[4]={};
        #pragma unroll
        for (int ks = 0; ks < 2; ++ks) {             // K=64: s then a
          const int kl = ks*32 + kg*8;
          bfrag a[4];
          #pragma unroll
          for (int fm = 0; fm < 4; ++fm) {
            int row = bmB + wv*64 + fm*16 + r16;
            a[fm] = (ks == 0)
              ? cvt8(&s0p[(size_t)row*32 + kg*8])
              : cvt8d(&s0p[(size_t)(BATCH + row)*32 + kg*8], &s0p[(size_t)row*32 + kg*8]);
          }
          bfrag bR = *(const bfrag*)&sm[(0*16+r16)*584 + kl];
          bfrag bZ = *(const bfrag*)&sm[(1*16+r16)*584 + kl];
          bfrag bN = *(const bfrag*)&sm[(2*16+r16)*584 + kl];
          #pragma unroll
          for (int fm = 0; fm < 4; ++fm) {
            R[fm]=MFMA(a[fm],bR,R[fm]); Z[fm]=MFMA(a[fm],bZ,Z[fm]); NI[fm]=MFMA(a[fm],bN,NI[fm]);
          }
        }
        #pragma unroll 2
        for (int kt = 0; kt < 16; ++kt) {            // K=512: h0
          const int kk = kt*32 + kg*8;
          const int kl = 64 + kk;
          bfrag a[4];
          #pragma unroll
          for (int fm = 0; fm < 4; ++fm) {
            int row = bmB + wv*64 + fm*16 + r16;
            a[fm] = *(const bfrag*)&h0r[(size_t)row*512 + kk];
          }
          bfrag bR = *(const bfrag*)&sm[(0*16+r16)*584 + kl];
          bfrag bZ = *(const bfrag*)&sm[(1*16+r16)*584 + kl];
          bfrag bN = *(const bfrag*)&sm[(2*16+r16)*584 + kl];
          #pragma unroll
          for (int fm = 0; fm < 4; ++fm) {
            R[fm]=MFMA(a[fm],bR,R[fm]); Z[fm]=MFMA(a[fm],bZ,Z[fm]); NH[fm]=MFMA(a[fm],bN,NH[fm]);
          }
        }
        unsigned short* exch = sm + 28032;          // [256][16]
        #pragma unroll
        for (int fm = 0; fm < 4; ++fm)
          #pragma unroll
          for (int e = 0; e < 4; ++e) {
            int rl = wv*64 + fm*16 + kg*4 + e;
            float r  = sigm(R[fm][e] + b0);
            float zg = sigm(Z[fm][e] + b1);
            float nn = tanhf(NI[fm][e] + b2 + r*(NH[fm][e] + b3));
            float hn = (1.f - zg)*nn + zg*hs[fm][e];
            hs[fm][e] = hn;
            exch[rl*16 + r16] = f2bf(hn);
          }
        __syncthreads();
        {
          unsigned short* dst = h0 + (size_t)ju*HB;        // h0(t) = step u
          int r = tid;
          u32x4 v0 = *(const u32x4*)&exch[r*16];
          u32x4 v1 = *(const u32x4*)&exch[r*16 + 8];
          unsigned short* dp = dst + ((size_t)(bmB + r))*512 + jt*16;
          st16_sc1(dp,     v0);
          st16_sc1(dp + 8, v1);
        }
      }
    } else if (xg == 6) {
      // ---------------- fc1, step t = u-1 ----------------
      if (u >= 1 && u <= 254) {
        const int bmB = (sub >> 3) * 128, bnB = (sub & 7) * 64;
        const unsigned short* h1r = h1 + (size_t)jm2*HB;   // h1(t-1)
        const float* s0p = P.states + (size_t)(u-1)*BATCH*32;
        f32x4 acc[4][2] = {};
        const int arow = bmB + (wv>>1)*64;
        const int bcol = (wv&1)*32;
        #pragma unroll 2
        for (int kt = 0; kt < 19; ++kt) {
          const int k = kt*32 + kg*8;
          bfrag a[4];
          #pragma unroll
          for (int fm = 0; fm < 4; ++fm) {
            int row = arow + fm*16 + r16;
            int rl  = row - bmB;
            if (kt == 0)      a[fm] = cvt8(&s0p[(size_t)row*32 + k]);
            else if (kt <= 2) a[fm] = *(const bfrag*)&sm[47616 + rl*64 + (k - 32)];
            else              a[fm] = *(const bfrag*)&h1r[(size_t)row*512 + (k - 96)];
          }
          bfrag bf0 = *(const bfrag*)&sm[(bcol      + r16)*616 + k];
          bfrag bf1 = *(const bfrag*)&sm[(bcol + 16 + r16)*616 + k];
          #pragma unroll
          for (int fm = 0; fm < 4; ++fm) {
            acc[fm][0] = MFMA(a[fm], bf0, acc[fm][0]);
            acc[fm][1] = MFMA(a[fm], bf1, acc[fm][1]);
          }
        }
        unsigned short* exch = sm + 39424;          // [128][64]
        #pragma unroll
        for (int fm = 0; fm < 4; ++fm)
          #pragma unroll
          for (int fn = 0; fn < 2; ++fn) {
            float bias = fn ? b1 : b0;
            #pragma unroll
            for (int e = 0; e < 4; ++e) {
              int rl = (wv>>1)*64 + fm*16 + kg*4 + e;
              int cl = bcol + fn*16 + r16;
              exch[rl*64 + cl] = f2bf(fmaxf(acc[fm][fn][e] + bias, 0.f));
            }
          }
        __syncthreads();
        {
          unsigned short* dst = d1 + (size_t)jm1*HB;       // dh1(t) = step u-1
          int r = tid >> 1, hc = tid & 1;
          #pragma unroll
          for (int q = 0; q < 4; ++q) {
            u32x4 v = *(const u32x4*)&exch[r*64 + hc*32 + q*8];
            st16_sc1(dst + ((size_t)(bmB + r))*512 + bnB + hc*32 + q*8, v);
          }
        }
        __syncthreads();
      }
    } else {
      // ---------------- fc2, step t = u-2 ----------------
      if (u >= 2 && u <= 255) {
        const int bmB = (sub >> 3) * 128, bnB = (sub & 7) * 64;
        const unsigned short* dr = d1 + (size_t)jm2*HB;    // dh1(t)
        f32x4 acc[4][2] = {};
        const int arow = bmB + (wv>>1)*64;
        const int bcol = (wv&1)*32;
        #pragma unroll 2
        for (int kt = 0; kt < 16; ++kt) {
          const int k = kt*32 + kg*8;
          bfrag a[4];
          #pragma unroll
          for (int fm = 0; fm < 4; ++fm) {
            int row = arow + fm*16 + r16;
            a[fm] = *(const bfrag*)&dr[(size_t)row*512 + k];
          }
          bfrag bf0 = *(const bfrag*)&sm[(bcol      + r16)*520 + k];
          bfrag bf1 = *(const bfrag*)&sm[(bcol + 16 + r16)*520 + k];
          #pragma unroll
          for (int fm = 0; fm < 4; ++fm) {
            acc[fm][0] = MFMA(a[fm], bf0, acc[fm][0]);
            acc[fm][1] = MFMA(a[fm], bf1, acc[fm][1]);
          }
        }
        unsigned short* exch = sm + 66560;          // [128][64]
        #pragma unroll
        for (int fm = 0; fm < 4; ++fm)
          #pragma unroll
          for (int fn = 0; fn < 2; ++fn) {
            float bias = fn ? b1 : b0;
            #pragma unroll
            for (int e = 0; e < 4; ++e) {
              int rl = (wv>>1)*64 + fm*16 + kg*4 + e;
              int cl = bcol + fn*16 + r16;
              exch[rl*64 + cl] = f2bf(fmaxf(acc[fm][fn][e] + bias, 0.f));
            }
          }
        __syncthreads();
        {
          unsigned short* dst = d2 + (size_t)jm2*HB;       // dh2(t) = step u-2
          int r = tid >> 1, hc = tid & 1;
          #pragma unroll
          for (int q = 0; q < 4; ++q) {
            u32x4 v = *(const u32x4*)&exch[r*64 + hc*32 + q*8];
            st16_sc1(dst + ((size_t)(bmB + r))*512 + bnB + hc*32 + q*8, v);
          }
        }
      }
      // ---------------- head, step t = u-3 ----------------
      if (u >= 3) {
        const int t = u - 3;
        const unsigned short* dr = d2 + (size_t)jm3*HB;    // dh2(u-3)
        f32x4 acc = {};
        #pragma unroll 2
        for (int kt = 0; kt < 16; ++kt) {
          const int k = kt*32 + kg*8;
          bfrag a = *(const bfrag*)&dr[(size_t)(sub*16 + r16)*512 + k];
          bfrag b = *(const bfrag*)&sm[33280 + (wv*16 + r16)*520 + k];
          acc = MFMA(a, b, acc);
        }
        __syncthreads();                    // fc2's exch use is done
        float* exch = (float*)(sm + 66560); // [16][66]
        const int c = wv*16 + r16;
        #pragma unroll
        for (int e = 0; e < 4; ++e)
          exch[(kg*4+e)*66 + c] = acc[e] + b2;
        __syncthreads();
        const float* s0p = P.states + (size_t)t*BATCH*32;
        #pragma unroll
        for (int e2 = 0; e2 < 2; ++e2) {
          int idx = tid*2 + e2;
          int r = idx >> 5, i = idx & 31;
          int b = sub*16 + r;
          float mean = exch[r*66 + i], lv = exch[r*66 + 32 + i];
          float av = s0p[(size_t)(BATCH + b)*32 + i] - s0p[(size_t)b*32 + i];
          float d = av - mean;
          float v = 0.5f*(d*d*__expf(-lv) + lv + LOG2PI);
          if (e2) nacc1 += v; else nacc0 += v;
        }
      }
    }

    // -------------------- publish --------------------
    __syncthreads();                      // drains all threads' sc1 stores
    if (tid == 0) ASTORE(&flags[blk*16], (unsigned)(u+1));
  }

  if (xg == 7) {
    #pragma unroll
    for (int e2 = 0; e2 < 2; ++e2) {
      int idx = tid*2 + e2;
      int b = sub*16 + (idx >> 5), i = idx & 31;
      P.out[(size_t)b*32 + i] = e2 ? nacc1 : nacc0;
    }
  }
}

extern "C" void kernel_launch(void* const* d_in, const int* in_sizes, int n_in,
                              void* d_out, int out_size, void* d_ws, size_t ws_size,
                              hipStream_t stream) {
  Params P;
  P.states = (const float*)d_in[0];
  P.zin    = (const float*)d_in[1];
  P.Wih0   = (const float*)d_in[2];
  P.Whh0   = (const float*)d_in[3];
  P.bih0   = (const float*)d_in[4];
  P.bhh0   = (const float*)d_in[5];
  P.Wih1   = (const float*)d_in[6];
  P.Whh1   = (const float*)d_in[7];
  P.bih1   = (const float*)d_in[8];
  P.bhh1   = (const float*)d_in[9];
  P.Wfc1   = (const float*)d_in[10];
  P.bfc1   = (const float*)d_in[11];
  P.Wfc2   = (const float*)d_in[12];
  P.bfc2   = (const float*)d_in[13];
  P.Wmean  = (const float*)d_in[14];
  P.bmean  = (const float*)d_in[15];
  P.Wlv    = (const float*)d_in[16];
  P.blv    = (const float*)d_in[17];
  P.out = (float*)d_out;
  P.act = (unsigned short*)d_ws;

  unsigned* flags = (unsigned*)(P.act + 32*(size_t)HB);   // 256 flags @ 64B
  unsigned* xcdf  = flags + 256*16;                       // 8 flags @ 64B

  // zero h0+h1 (all 8 slots each; initial h = 0), flags+xcdf, out
  hipMemsetAsync(P.act, 0, 16*(size_t)HB*sizeof(unsigned short), stream);
  hipMemsetAsync(flags, 0, (256*16 + 8*16)*sizeof(unsigned), stream);
  hipMemsetAsync(d_out, 0, (size_t)out_size*sizeof(float), stream);

  fused<<<dim3(256), dim3(256), 0, stream>>>(P, flags, xcdf);
}